// Round 6
// baseline (630.961 us; speedup 1.0000x reference)
//
#include <hip/hip_runtime.h>
#include <hip/hip_bf16.h>

#define N_NODES 100000
#define N_EDGES 3200000
#define D_FEAT  256
#define UNITS   256

#define BROWS   128                      // rows per bucket
#define NB      782                      // ceil(100000/128)
#define NCHUNK  256                      // blocks for hist/scatter
#define EPB     (N_EDGES / NCHUNK)       // 12500 edges per block (exact)
#define MAXB    6144                     // bucket capacity (mean 4096, sigma ~64)

using frag_ab = __attribute__((ext_vector_type(8))) short;   // 8 bf16 = 4 VGPRs
using frag_cd = __attribute__((ext_vector_type(4))) float;   // 4 fp32 acc

__device__ __forceinline__ float bf2f(unsigned short u) {
    union { unsigned int i; float f; } c; c.i = ((unsigned int)u) << 16; return c.f;
}
__device__ __forceinline__ unsigned short f2bf(float f) {
    union { float f; unsigned int i; } c; c.f = f;
    unsigned int r = c.i + 0x7FFF + ((c.i >> 16) & 1);   // round-nearest-even
    return (unsigned short)(r >> 16);
}

// ---------------- W fp32 [k][n] -> bf16 W^T [n][k] ----------------
__global__ __launch_bounds__(256) void convert_wt(const float* __restrict__ W,
                                                  unsigned short* __restrict__ Wt) {
    const int n = blockIdx.x, k = threadIdx.x;
    Wt[n * 256 + k] = f2bf(W[k * 256 + n]);
}

// ------- GEMM: h = X @ W, BM=128 BN=256 (single column pass, X read once) -------
__global__ __launch_bounds__(256) void gemm_mfma(const float* __restrict__ X,
                                                 const unsigned short* __restrict__ Wt,
                                                 unsigned short* __restrict__ hb) {
    __shared__ unsigned short As[128 * 32];   // [m][k] bf16, 8 KB
    __shared__ unsigned short Bs[256 * 32];   // [n][k] bf16, 16 KB
    const int t    = threadIdx.x;
    const int lane = t & 63;
    const int wave = t >> 6;
    const int wm   = (wave >> 1) * 64;        // 0 or 64   (rows)
    const int wn   = (wave & 1) * 128;        // 0 or 128  (cols)
    const int rowBase = blockIdx.x * 128;
    const int lr = lane & 15, lq = lane >> 4;

    frag_cd acc[4][8];
    #pragma unroll
    for (int i = 0; i < 4; ++i)
        #pragma unroll
        for (int j = 0; j < 8; ++j)
            acc[i][j] = (frag_cd){0.f, 0.f, 0.f, 0.f};

    for (int k0 = 0; k0 < D_FEAT; k0 += 32) {
        // A tile: 128 rows x 32 k of X (fp32) -> bf16 (1024 float4 chunks)
        #pragma unroll
        for (int cc = 0; cc < 4; ++cc) {
            const int c = t + cc * 256;
            const int r = c >> 3, fo = (c & 7) * 4;
            const int grow = min(rowBase + r, N_NODES - 1);   // clamp; excess never stored
            const float4 xv = *(const float4*)(X + (size_t)grow * D_FEAT + k0 + fo);
            ushort4 o;
            o.x = f2bf(xv.x); o.y = f2bf(xv.y); o.z = f2bf(xv.z); o.w = f2bf(xv.w);
            *(ushort4*)(As + r * 32 + fo) = o;
        }
        // B tile: 256 n x 32 k bf16 (1024 16B chunks)
        #pragma unroll
        for (int cc = 0; cc < 4; ++cc) {
            const int c = t + cc * 256;
            const int n = c >> 2, ko = (c & 3) * 8;
            *(uint4*)(Bs + n * 32 + ko) =
                *(const uint4*)(Wt + (size_t)n * 256 + k0 + ko);
        }
        __syncthreads();

        frag_ab a[4], b[8];
        #pragma unroll
        for (int i = 0; i < 4; ++i)
            a[i] = *(const frag_ab*)(As + (wm + i * 16 + lr) * 32 + lq * 8);
        #pragma unroll
        for (int j = 0; j < 8; ++j)
            b[j] = *(const frag_ab*)(Bs + (wn + j * 16 + lr) * 32 + lq * 8);

        #pragma unroll
        for (int i = 0; i < 4; ++i)
            #pragma unroll
            for (int j = 0; j < 8; ++j)
                acc[i][j] = __builtin_amdgcn_mfma_f32_16x16x32_bf16(
                    a[i], b[j], acc[i][j], 0, 0, 0);
        __syncthreads();
    }

    // epilogue: C/D layout col=lane&15, row=(lane>>4)*4+reg
    #pragma unroll
    for (int i = 0; i < 4; ++i) {
        #pragma unroll
        for (int rr = 0; rr < 4; ++rr) {
            const int row = rowBase + wm + i * 16 + lq * 4 + rr;
            if (row < N_NODES) {
                #pragma unroll
                for (int j = 0; j < 8; ++j) {
                    hb[(size_t)row * 256 + wn + j * 16 + lr] =
                        f2bf(acc[i][j][rr]);
                }
            }
        }
    }
}

// ---------------- K1: per-block bucket histogram (bucket-major output) ----------------
__global__ __launch_bounds__(256) void hist_kernel(const int* __restrict__ erow,
                                                   int* __restrict__ hist_g) {
    __shared__ int h[NB];
    const int t = threadIdx.x;
    const int b = blockIdx.x;
    for (int i = t; i < NB; i += 256) h[i] = 0;
    __syncthreads();
    const int base_e = b * EPB;
    for (int i = t; i < EPB; i += 256)
        atomicAdd(&h[erow[base_e + i] >> 7], 1);
    __syncthreads();
    for (int i = t; i < NB; i += 256)
        hist_g[i * NCHUNK + b] = h[i];        // transposed: [bucket][block]
}

// ---------------- K2a: per-bucket scan over blocks (coalesced read) ----------------
__global__ __launch_bounds__(256) void scan_buckets(const int* __restrict__ hist_g,
                                                    int* __restrict__ cum,
                                                    int* __restrict__ total) {
    const int k = blockIdx.x, t = threadIdx.x;
    __shared__ int p[256];
    const int v = hist_g[k * NCHUNK + t];
    p[t] = v;
    __syncthreads();
    for (int d = 1; d < 256; d <<= 1) {
        const int u = (t >= d) ? p[t - d] : 0;
        __syncthreads();
        p[t] += u;
        __syncthreads();
    }
    cum[k * NCHUNK + t] = p[t] - v;            // exclusive prefix
    if (t == 255) total[k] = p[255];
}

// ---------------- K2b: scan bucket totals -> base offsets ----------------
__global__ __launch_bounds__(1024) void scan_base(const int* __restrict__ total,
                                                  int* __restrict__ base) {
    const int t = threadIdx.x;
    __shared__ int p[1024];
    const int v = (t < NB) ? total[t] : 0;
    p[t] = v;
    __syncthreads();
    for (int d = 1; d < 1024; d <<= 1) {
        const int u = (t >= d) ? p[t - d] : 0;
        __syncthreads();
        p[t] += u;
        __syncthreads();
    }
    if (t < NB) base[t] = p[t] - v;
    if (t == NB - 1) base[NB] = p[t];
}

// ---------------- K3: binned scatter, private ranges (LDS atomics only) ----------------
__global__ __launch_bounds__(256) void scatter_binned(const int* __restrict__ erow,
                                                      const int* __restrict__ ecol,
                                                      const float* __restrict__ eval,
                                                      const int* __restrict__ cum,
                                                      const int* __restrict__ base,
                                                      uint2* __restrict__ binned) {
    __shared__ int cur[NB];
    const int t = threadIdx.x;
    const int b = blockIdx.x;
    for (int i = t; i < NB; i += 256)
        cur[i] = base[i] + cum[i * NCHUNK + b];
    __syncthreads();
    const int base_e = b * EPB;
    for (int i = t; i < EPB; i += 256) {
        const int e = base_e + i;
        const int r = erow[e];
        const int c = ecol[e];
        const float v = eval[e];
        const int k = r >> 7, rl = r & 127;
        const int pos = atomicAdd(&cur[k], 1);          // LDS atomic
        binned[pos] = make_uint2(((unsigned)rl << 17) | (unsigned)c,
                                 __float_as_uint(v));
    }
}

// -------- K4: fused per-bucket sort + SpMM + bias + ReLU (no sorted round-trip) --------
__global__ __launch_bounds__(512) void sort_spmm(const uint2* __restrict__ binned,
                                                 const int* __restrict__ base,
                                                 const int* __restrict__ total,
                                                 const unsigned short* __restrict__ hb,
                                                 const float* __restrict__ bias,
                                                 float* __restrict__ out) {
    __shared__ uint2 buf[MAXB];                 // 48 KB: bucket edges, row-sorted
    __shared__ int lh[BROWS], loff[BROWS], lcur[BROWS];
    const int k = blockIdx.x, t = threadIdx.x;
    const int s = base[k];
    const int cnt = min(total[k], MAXB);

    // pass 1: row histogram
    if (t < BROWS) lh[t] = 0;
    __syncthreads();
    for (int i = t; i < cnt; i += 512)
        atomicAdd(&lh[binned[s + i].x >> 17], 1);
    __syncthreads();
    // inclusive scan of lh -> loff
    if (t < BROWS) loff[t] = lh[t];
    __syncthreads();
    for (int d = 1; d < BROWS; d <<= 1) {
        const int u = (t >= d && t < BROWS) ? loff[t - d] : 0;
        __syncthreads();
        if (t < BROWS) loff[t] += u;
        __syncthreads();
    }
    if (t < BROWS) lcur[t] = loff[t] - lh[t];   // exclusive start
    __syncthreads();
    // pass 2: scatter into LDS, row-sorted (binned re-read is L2-hot)
    for (int i = t; i < cnt; i += 512) {
        const uint2 eo = binned[s + i];
        const int rl = eo.x >> 17;
        const int p = atomicAdd(&lcur[rl], 1);  // LDS atomic
        buf[p] = make_uint2(eo.x & 0x1FFFF, eo.y);
    }
    __syncthreads();

    // pass 3: 8 waves x 16 rows each; gather h rows, accumulate in regs
    const int wave = t >> 6, lane = t & 63;
    const float4 b4 = *(const float4*)(bias + lane * 4);
    #pragma unroll 1
    for (int rr = 0; rr < 16; ++rr) {
        const int rl  = wave * 16 + rr;
        const int row = k * BROWS + rl;
        if (row >= N_NODES) break;              // wave-uniform
        const int e1 = loff[rl];
        int j = e1 - lh[rl];
        float a0 = 0.f, a1 = 0.f, a2 = 0.f, a3 = 0.f;
        #pragma unroll 2
        for (; j < e1; ++j) {
            const uint2 cv = buf[j];
            const float v = __uint_as_float(cv.y);
            const ushort4 hv = *(const ushort4*)(hb + (size_t)cv.x * 256 + lane * 4);
            a0 += v * bf2f(hv.x);
            a1 += v * bf2f(hv.y);
            a2 += v * bf2f(hv.z);
            a3 += v * bf2f(hv.w);
        }
        float4 o;
        o.x = fmaxf(a0 + b4.x, 0.f);
        o.y = fmaxf(a1 + b4.y, 0.f);
        o.z = fmaxf(a2 + b4.z, 0.f);
        o.w = fmaxf(a3 + b4.w, 0.f);
        *(float4*)(out + (size_t)row * 256 + lane * 4) = o;
    }
}

// ---------------- launch ----------------
extern "C" void kernel_launch(void* const* d_in, const int* in_sizes, int n_in,
                              void* d_out, int out_size, void* d_ws, size_t ws_size,
                              hipStream_t stream) {
    const float* X    = (const float*)d_in[0];
    const int*   erow = (const int*)  d_in[1];
    const int*   ecol = (const int*)  d_in[2];
    const float* evalv= (const float*)d_in[3];
    const float* W    = (const float*)d_in[4];
    const float* bias = (const float*)d_in[5];
    float* out = (float*)d_out;

    char* ws = (char*)d_ws;
    size_t off = 0;
    auto alloc = [&](size_t bytes) {
        void* p = ws + off;
        off += (bytes + 255) & ~(size_t)255;
        return p;
    };
    unsigned short* Wt     = (unsigned short*)alloc((size_t)D_FEAT * UNITS * 2);
    unsigned short* hb     = (unsigned short*)alloc((size_t)N_NODES * UNITS * 2);
    uint2*          binned = (uint2*)         alloc((size_t)N_EDGES * 8);
    int*            hist_g = (int*)           alloc((size_t)NCHUNK * NB * 4);
    int*            cum    = (int*)           alloc((size_t)NCHUNK * NB * 4);
    int*            total  = (int*)           alloc((size_t)NB * 4);
    int*            basep  = (int*)           alloc((size_t)(NB + 1) * 4);

    convert_wt<<<UNITS, 256, 0, stream>>>(W, Wt);
    gemm_mfma<<<(N_NODES + 127) / 128, 256, 0, stream>>>(X, Wt, hb);
    hist_kernel<<<NCHUNK, 256, 0, stream>>>(erow, hist_g);
    scan_buckets<<<NB, 256, 0, stream>>>(hist_g, cum, total);
    scan_base<<<1, 1024, 0, stream>>>(total, basep);
    scatter_binned<<<NCHUNK, 256, 0, stream>>>(erow, ecol, evalv, cum, basep, binned);
    sort_spmm<<<NB, 512, 0, stream>>>(binned, basep, total, hb, bias, out);
}